// Round 1
// baseline (408.746 us; speedup 1.0000x reference)
//
#include <hip/hip_runtime.h>

#define H 1024
#define S 65536

// K1: v[j] = sum_i W[i][j] * hidden[i]   (W row-major [H,H])
// Consecutive threads -> consecutive columns j -> coalesced W reads.
__global__ __launch_bounds__(256) void k_compute_v(const float* __restrict__ W,
                                                   const float* __restrict__ hidden,
                                                   float* __restrict__ v) {
    __shared__ float sh[H];
    const int t = threadIdx.x;
    for (int i = t; i < H; i += 256) sh[i] = hidden[i];
    __syncthreads();
    const int j = blockIdx.x * 256 + t;
    float a0 = 0.f, a1 = 0.f, a2 = 0.f, a3 = 0.f;
    for (int i = 0; i < H; i += 4) {
        a0 += W[(size_t)(i + 0) * H + j] * sh[i + 0];
        a1 += W[(size_t)(i + 1) * H + j] * sh[i + 1];
        a2 += W[(size_t)(i + 2) * H + j] * sh[i + 2];
        a3 += W[(size_t)(i + 3) * H + j] * sh[i + 3];
    }
    v[j] = (a0 + a1) + (a2 + a3);
}

// K2: scores[row] = enc[row] . v  (wave-per-row, v fragment in registers)
// Lane l holds v[4*l + 256*k], k=0..3 (16 floats). Per row: 4 coalesced
// float4 loads (1 KiB/wave/instr), 16 FMAs, 6-shfl butterfly.
__global__ __launch_bounds__(256) void k_scores(const float* __restrict__ enc,
                                                const float* __restrict__ v,
                                                float* __restrict__ scores,
                                                float* __restrict__ bmax) {
    const int lane = threadIdx.x & 63;
    const int warp = threadIdx.x >> 6;
    const float4* v4 = (const float4*)v;
    const float4 vr0 = v4[lane];
    const float4 vr1 = v4[lane + 64];
    const float4 vr2 = v4[lane + 128];
    const float4 vr3 = v4[lane + 192];

    const int wave_global = blockIdx.x * 4 + warp;  // 0..4095
    const float4* e4 = (const float4*)enc;
    float wmax = -INFINITY;

    for (int it = 0; it < 16; ++it) {
        const int row = wave_global + it * 4096;
        const float4* e = e4 + (size_t)row * 256;
        const float4 a0 = e[lane];
        const float4 a1 = e[lane + 64];
        const float4 a2 = e[lane + 128];
        const float4 a3 = e[lane + 192];
        float acc = a0.x * vr0.x + a0.y * vr0.y + a0.z * vr0.z + a0.w * vr0.w
                  + a1.x * vr1.x + a1.y * vr1.y + a1.z * vr1.z + a1.w * vr1.w
                  + a2.x * vr2.x + a2.y * vr2.y + a2.z * vr2.z + a2.w * vr2.w
                  + a3.x * vr3.x + a3.y * vr3.y + a3.z * vr3.z + a3.w * vr3.w;
        #pragma unroll
        for (int m = 1; m < 64; m <<= 1) acc += __shfl_xor(acc, m, 64);
        if (lane == 0) scores[row] = acc;
        wmax = fmaxf(wmax, acc);  // acc identical on all lanes after butterfly
    }

    __shared__ float smax[4];
    if (lane == 0) smax[warp] = wmax;
    __syncthreads();
    if (threadIdx.x == 0)
        bmax[blockIdx.x] = fmaxf(fmaxf(smax[0], smax[1]), fmaxf(smax[2], smax[3]));
}

// K3: every block redundantly reduces bmax[1024] -> gmax (L2-hot, cheap),
// writes exp(score - gmax) to out, and its 256-element partial sum to bsum.
__global__ __launch_bounds__(256) void k_exp(const float* __restrict__ scores,
                                             const float* __restrict__ bmax,
                                             float* __restrict__ out,
                                             float* __restrict__ bsum) {
    const int t = threadIdx.x;
    const int lane = t & 63;
    const int warp = t >> 6;

    float m = fmaxf(fmaxf(bmax[t], bmax[t + 256]),
                    fmaxf(bmax[t + 512], bmax[t + 768]));
    #pragma unroll
    for (int d = 1; d < 64; d <<= 1) m = fmaxf(m, __shfl_xor(m, d, 64));
    __shared__ float sm[4];
    if (lane == 0) sm[warp] = m;
    __syncthreads();
    const float gmax = fmaxf(fmaxf(sm[0], sm[1]), fmaxf(sm[2], sm[3]));

    const int i = blockIdx.x * 256 + t;
    const float e = __expf(scores[i] - gmax);
    out[i] = e;

    float s = e;
    #pragma unroll
    for (int d = 1; d < 64; d <<= 1) s += __shfl_xor(s, d, 64);
    __shared__ float ss[4];
    if (lane == 0) ss[warp] = s;
    __syncthreads();
    if (t == 0) bsum[blockIdx.x] = (ss[0] + ss[1]) + (ss[2] + ss[3]);
}

// K4: every block redundantly reduces bsum[256] -> total, scales its chunk.
__global__ __launch_bounds__(256) void k_norm(const float* __restrict__ bsum,
                                              float* __restrict__ out) {
    const int t = threadIdx.x;
    const int lane = t & 63;
    const int warp = t >> 6;

    float s = bsum[t];
    #pragma unroll
    for (int d = 1; d < 64; d <<= 1) s += __shfl_xor(s, d, 64);
    __shared__ float ss[4];
    if (lane == 0) ss[warp] = s;
    __syncthreads();
    const float inv = 1.0f / ((ss[0] + ss[1]) + (ss[2] + ss[3]));

    const int i = blockIdx.x * 256 + t;
    out[i] *= inv;
}

extern "C" void kernel_launch(void* const* d_in, const int* in_sizes, int n_in,
                              void* d_out, int out_size, void* d_ws, size_t ws_size,
                              hipStream_t stream) {
    const float* hidden = (const float*)d_in[0];
    const float* enc    = (const float*)d_in[1];
    const float* W      = (const float*)d_in[2];
    // d_in[3] = b: b.hidden is a uniform shift of all scores -> softmax-invariant, dropped.
    float* out = (float*)d_out;

    float* v      = (float*)d_ws;   // 1024
    float* scores = v + 1024;       // 65536
    float* bmax   = scores + S;     // 1024
    float* bsum   = bmax + 1024;    // 256

    k_compute_v<<<4,    256, 0, stream>>>(W, hidden, v);
    k_scores   <<<1024, 256, 0, stream>>>(enc, v, scores, bmax);
    k_exp      <<<256,  256, 0, stream>>>(scores, bmax, out, bsum);
    k_norm     <<<256,  256, 0, stream>>>(bsum, out);
}

// Round 2
// 384.562 us; speedup vs baseline: 1.0629x; 1.0629x over previous
//
#include <hip/hip_runtime.h>

#define H 1024
#define S 65536

// K1a: split-K partial GEMV. Block b computes partial[b][j] = sum over its
// 8 rows of W[i][j]*h[i], j = all 1024 columns (float4 per thread).
// 128 blocks -> 128 CUs stream the 4 MB of W in ~1-2 us instead of 4 CUs/44 us.
__global__ __launch_bounds__(256) void k1a_partial(const float* __restrict__ W,
                                                   const float* __restrict__ hidden,
                                                   float* __restrict__ partial) {
    const int t = threadIdx.x;
    const int b = blockIdx.x;            // 0..127
    const int i0 = b * 8;                // 8 rows per block
    const float4* W4 = (const float4*)W; // row stride = 256 float4
    float4 acc = make_float4(0.f, 0.f, 0.f, 0.f);
    #pragma unroll
    for (int r = 0; r < 8; ++r) {
        const float hv = hidden[i0 + r];             // wave-uniform broadcast
        const float4 w = W4[(size_t)(i0 + r) * 256 + t];
        acc.x += w.x * hv; acc.y += w.y * hv;
        acc.z += w.z * hv; acc.w += w.w * hv;
    }
    ((float4*)partial)[(size_t)b * 256 + t] = acc;
}

// K1b: v[j] = sum_b partial[b][j]. 4 blocks, L2-hot (512 KB), ~2 us.
__global__ __launch_bounds__(256) void k1b_reduce(const float* __restrict__ partial,
                                                  float* __restrict__ v) {
    const int j = blockIdx.x * 256 + threadIdx.x;
    float s0 = 0.f, s1 = 0.f;
    for (int b = 0; b < 128; b += 2) {
        s0 += partial[(size_t)b * H + j];
        s1 += partial[(size_t)(b + 1) * H + j];
    }
    v[j] = s0 + s1;
}

// K2: scores[row] = enc[row] . v  (wave-per-row, v fragment in registers)
// Lane l holds v[4*l + 256*k], k=0..3 (16 floats). Per row: 4 coalesced
// float4 loads (1 KiB/wave/instr), 16 FMAs, 6-shfl butterfly. HBM-bound.
__global__ __launch_bounds__(256) void k_scores(const float* __restrict__ enc,
                                                const float* __restrict__ v,
                                                float* __restrict__ scores,
                                                float* __restrict__ bmax) {
    const int lane = threadIdx.x & 63;
    const int warp = threadIdx.x >> 6;
    const float4* v4 = (const float4*)v;
    const float4 vr0 = v4[lane];
    const float4 vr1 = v4[lane + 64];
    const float4 vr2 = v4[lane + 128];
    const float4 vr3 = v4[lane + 192];

    const int wave_global = blockIdx.x * 4 + warp;  // 0..4095
    const float4* e4 = (const float4*)enc;
    float wmax = -INFINITY;

    for (int it = 0; it < 16; ++it) {
        const int row = wave_global + it * 4096;
        const float4* e = e4 + (size_t)row * 256;
        const float4 a0 = e[lane];
        const float4 a1 = e[lane + 64];
        const float4 a2 = e[lane + 128];
        const float4 a3 = e[lane + 192];
        float acc = a0.x * vr0.x + a0.y * vr0.y + a0.z * vr0.z + a0.w * vr0.w
                  + a1.x * vr1.x + a1.y * vr1.y + a1.z * vr1.z + a1.w * vr1.w
                  + a2.x * vr2.x + a2.y * vr2.y + a2.z * vr2.z + a2.w * vr2.w
                  + a3.x * vr3.x + a3.y * vr3.y + a3.z * vr3.z + a3.w * vr3.w;
        #pragma unroll
        for (int m = 1; m < 64; m <<= 1) acc += __shfl_xor(acc, m, 64);
        if (lane == 0) scores[row] = acc;
        wmax = fmaxf(wmax, acc);  // acc identical on all lanes after butterfly
    }

    __shared__ float smax[4];
    if (lane == 0) smax[warp] = wmax;
    __syncthreads();
    if (threadIdx.x == 0)
        bmax[blockIdx.x] = fmaxf(fmaxf(smax[0], smax[1]), fmaxf(smax[2], smax[3]));
}

// K3: every block redundantly reduces bmax[1024] -> gmax (L2-hot, cheap),
// writes exp(score - gmax) to out, and its 256-element partial sum to bsum.
__global__ __launch_bounds__(256) void k_exp(const float* __restrict__ scores,
                                             const float* __restrict__ bmax,
                                             float* __restrict__ out,
                                             float* __restrict__ bsum) {
    const int t = threadIdx.x;
    const int lane = t & 63;
    const int warp = t >> 6;

    float m = fmaxf(fmaxf(bmax[t], bmax[t + 256]),
                    fmaxf(bmax[t + 512], bmax[t + 768]));
    #pragma unroll
    for (int d = 1; d < 64; d <<= 1) m = fmaxf(m, __shfl_xor(m, d, 64));
    __shared__ float sm[4];
    if (lane == 0) sm[warp] = m;
    __syncthreads();
    const float gmax = fmaxf(fmaxf(sm[0], sm[1]), fmaxf(sm[2], sm[3]));

    const int i = blockIdx.x * 256 + t;
    const float e = __expf(scores[i] - gmax);
    out[i] = e;

    float s = e;
    #pragma unroll
    for (int d = 1; d < 64; d <<= 1) s += __shfl_xor(s, d, 64);
    __shared__ float ss[4];
    if (lane == 0) ss[warp] = s;
    __syncthreads();
    if (t == 0) bsum[blockIdx.x] = (ss[0] + ss[1]) + (ss[2] + ss[3]);
}

// K4: every block redundantly reduces bsum[256] -> total, scales its chunk.
__global__ __launch_bounds__(256) void k_norm(const float* __restrict__ bsum,
                                              float* __restrict__ out) {
    const int t = threadIdx.x;
    const int lane = t & 63;
    const int warp = t >> 6;

    float s = bsum[t];
    #pragma unroll
    for (int d = 1; d < 64; d <<= 1) s += __shfl_xor(s, d, 64);
    __shared__ float ss[4];
    if (lane == 0) ss[warp] = s;
    __syncthreads();
    const float inv = 1.0f / ((ss[0] + ss[1]) + (ss[2] + ss[3]));

    const int i = blockIdx.x * 256 + t;
    out[i] *= inv;
}

extern "C" void kernel_launch(void* const* d_in, const int* in_sizes, int n_in,
                              void* d_out, int out_size, void* d_ws, size_t ws_size,
                              hipStream_t stream) {
    const float* hidden = (const float*)d_in[0];
    const float* enc    = (const float*)d_in[1];
    const float* W      = (const float*)d_in[2];
    // d_in[3] = b: b.hidden is a uniform shift of all scores -> softmax-invariant, dropped.
    float* out = (float*)d_out;

    float* v       = (float*)d_ws;       // 1024
    float* scores  = v + 1024;           // 65536
    float* bmax    = scores + S;         // 1024
    float* bsum    = bmax + 1024;        // 256
    float* partial = bsum + 256;         // 128*1024

    k1a_partial<<<128,  256, 0, stream>>>(W, hidden, partial);
    k1b_reduce <<<4,    256, 0, stream>>>(partial, v);
    k_scores   <<<1024, 256, 0, stream>>>(enc, v, scores, bmax);
    k_exp      <<<256,  256, 0, stream>>>(scores, bmax, out, bsum);
    k_norm     <<<256,  256, 0, stream>>>(bsum, out);
}

// Round 4
// 359.827 us; speedup vs baseline: 1.1360x; 1.0687x over previous
//
#include <hip/hip_runtime.h>

#define H 1024
#define S 65536

typedef float vfloat4 __attribute__((ext_vector_type(4)));  // native vec for nontemporal builtins

__device__ __forceinline__ vfloat4 nt_load4(const float* p) {
    return __builtin_nontemporal_load((const vfloat4*)p);
}

// K1a: split-K partial GEMV. Block b computes partial[b][j] = sum over its
// 8 rows of W[i][j]*h[i], j = all 1024 columns (float4 per thread).
__global__ __launch_bounds__(256) void k1a_partial(const float* __restrict__ W,
                                                   const float* __restrict__ hidden,
                                                   float* __restrict__ partial) {
    const int t = threadIdx.x;
    const int b = blockIdx.x;            // 0..127
    const int i0 = b * 8;                // 8 rows per block
    vfloat4 acc = (vfloat4)(0.f);
    #pragma unroll
    for (int r = 0; r < 8; ++r) {
        const float hv = hidden[i0 + r];             // wave-uniform broadcast
        const vfloat4 w = nt_load4(W + (size_t)(i0 + r) * H + t * 4);
        acc += w * hv;
    }
    *(vfloat4*)(partial + (size_t)b * H + t * 4) = acc;
}

// K1b: v[j] = sum_b partial[b][j]. 4 blocks, L2-hot (512 KB).
__global__ __launch_bounds__(256) void k1b_reduce(const float* __restrict__ partial,
                                                  float* __restrict__ v) {
    const int j = blockIdx.x * 256 + threadIdx.x;
    float s0 = 0.f, s1 = 0.f;
    for (int b = 0; b < 128; b += 2) {
        s0 += partial[(size_t)b * H + j];
        s1 += partial[(size_t)(b + 1) * H + j];
    }
    v[j] = s0 + s1;
}

// K2: scores[row] = enc[row] . v. Wave handles 2 rows/iter (8 float4 loads in
// flight), paired butterfly (7 shfl for 2 rows instead of 12). Nontemporal
// loads on the 256 MB read-once stream.
__global__ __launch_bounds__(256) void k_scores(const float* __restrict__ enc,
                                                const float* __restrict__ v,
                                                float* __restrict__ scores,
                                                float* __restrict__ bmax) {
    const int lane = threadIdx.x & 63;
    const int warp = threadIdx.x >> 6;
    const vfloat4 vr0 = *(const vfloat4*)(v + lane * 4);
    const vfloat4 vr1 = *(const vfloat4*)(v + 256 + lane * 4);
    const vfloat4 vr2 = *(const vfloat4*)(v + 512 + lane * 4);
    const vfloat4 vr3 = *(const vfloat4*)(v + 768 + lane * 4);

    const int wg = blockIdx.x * 4 + warp;  // 0..4095
    float wmax = -INFINITY;

    for (int it = 0; it < 8; ++it) {
        const int r0 = wg * 2 + it * 8192;
        const int r1 = r0 + 1;
        const float* e0 = enc + (size_t)r0 * H;
        const float* e1 = enc + (size_t)r1 * H;
        const vfloat4 a0 = nt_load4(e0 + lane * 4);
        const vfloat4 a1 = nt_load4(e0 + 256 + lane * 4);
        const vfloat4 a2 = nt_load4(e0 + 512 + lane * 4);
        const vfloat4 a3 = nt_load4(e0 + 768 + lane * 4);
        const vfloat4 b0 = nt_load4(e1 + lane * 4);
        const vfloat4 b1 = nt_load4(e1 + 256 + lane * 4);
        const vfloat4 b2 = nt_load4(e1 + 512 + lane * 4);
        const vfloat4 b3 = nt_load4(e1 + 768 + lane * 4);
        const vfloat4 p0 = a0 * vr0 + a1 * vr1 + a2 * vr2 + a3 * vr3;
        const vfloat4 p1 = b0 * vr0 + b1 * vr1 + b2 * vr2 + b3 * vr3;
        float acc0 = (p0.x + p0.y) + (p0.z + p0.w);
        float acc1 = (p1.x + p1.y) + (p1.z + p1.w);
        // Fold the two rows into the two half-waves, then one 32-lane butterfly.
        const float t0 = __shfl_xor(acc0, 32, 64);
        const float t1 = __shfl_xor(acc1, 32, 64);
        float c = (lane < 32) ? (acc0 + t0) : (acc1 + t1);
        #pragma unroll
        for (int m = 1; m < 32; m <<= 1) c += __shfl_xor(c, m, 64);
        // lanes 0..31 hold sum(r0); lanes 32..63 hold sum(r1)
        if (lane == 0)  scores[r0] = c;
        if (lane == 32) scores[r1] = c;
        wmax = fmaxf(wmax, c);
    }
    wmax = fmaxf(wmax, __shfl_xor(wmax, 32, 64));  // merge half-wave maxes

    __shared__ float smax[4];
    if (lane == 0) smax[warp] = wmax;
    __syncthreads();
    if (threadIdx.x == 0)
        bmax[blockIdx.x] = fmaxf(fmaxf(smax[0], smax[1]), fmaxf(smax[2], smax[3]));
}

// K3: every block redundantly reduces bmax[1024] -> gmax (L2-hot, cheap),
// writes exp(score - gmax) to out, and its 256-element partial sum to bsum.
__global__ __launch_bounds__(256) void k_exp(const float* __restrict__ scores,
                                             const float* __restrict__ bmax,
                                             float* __restrict__ out,
                                             float* __restrict__ bsum) {
    const int t = threadIdx.x;
    const int lane = t & 63;
    const int warp = t >> 6;

    float m = fmaxf(fmaxf(bmax[t], bmax[t + 256]),
                    fmaxf(bmax[t + 512], bmax[t + 768]));
    #pragma unroll
    for (int d = 1; d < 64; d <<= 1) m = fmaxf(m, __shfl_xor(m, d, 64));
    __shared__ float sm[4];
    if (lane == 0) sm[warp] = m;
    __syncthreads();
    const float gmax = fmaxf(fmaxf(sm[0], sm[1]), fmaxf(sm[2], sm[3]));

    const int i = blockIdx.x * 256 + t;
    const float e = __expf(scores[i] - gmax);
    out[i] = e;

    float s = e;
    #pragma unroll
    for (int d = 1; d < 64; d <<= 1) s += __shfl_xor(s, d, 64);
    __shared__ float ss[4];
    if (lane == 0) ss[warp] = s;
    __syncthreads();
    if (t == 0) bsum[blockIdx.x] = (ss[0] + ss[1]) + (ss[2] + ss[3]);
}

// K4: every block redundantly reduces bsum[256] -> total, scales its chunk.
__global__ __launch_bounds__(256) void k_norm(const float* __restrict__ bsum,
                                              float* __restrict__ out) {
    const int t = threadIdx.x;
    const int lane = t & 63;
    const int warp = t >> 6;

    float s = bsum[t];
    #pragma unroll
    for (int d = 1; d < 64; d <<= 1) s += __shfl_xor(s, d, 64);
    __shared__ float ss[4];
    if (lane == 0) ss[warp] = s;
    __syncthreads();
    const float inv = 1.0f / ((ss[0] + ss[1]) + (ss[2] + ss[3]));

    const int i = blockIdx.x * 256 + t;
    out[i] *= inv;
}

extern "C" void kernel_launch(void* const* d_in, const int* in_sizes, int n_in,
                              void* d_out, int out_size, void* d_ws, size_t ws_size,
                              hipStream_t stream) {
    const float* hidden = (const float*)d_in[0];
    const float* enc    = (const float*)d_in[1];
    const float* W      = (const float*)d_in[2];
    // d_in[3] = b: b.hidden is a uniform shift of all scores -> softmax-invariant, dropped.
    float* out = (float*)d_out;

    float* v       = (float*)d_ws;       // 1024
    float* scores  = v + 1024;           // 65536
    float* bmax    = scores + S;         // 1024
    float* bsum    = bmax + 1024;        // 256
    float* partial = bsum + 256;         // 128*1024

    k1a_partial<<<128,  256, 0, stream>>>(W, hidden, partial);
    k1b_reduce <<<4,    256, 0, stream>>>(partial, v);
    k_scores   <<<1024, 256, 0, stream>>>(enc, v, scores, bmax);
    k_exp      <<<256,  256, 0, stream>>>(scores, bmax, out, bsum);
    k_norm     <<<256,  256, 0, stream>>>(bsum, out);
}